// Round 4
// baseline (19.562 us; speedup 1.0000x reference)
//
#include <hip/hip_runtime.h>
#include <math.h>

// SSKernelDiag: K[h,l] = 2*Re( sum_n Cb[h,n] * exp(dtA[h,n]*l) )
// Chebyshev recurrence sampled at stride T=TPB:
//   y_{k+1} = c1*y_k + c2*y_{k-1},  c1 = 2*Re(W), c2 = -|W|^2, W = w^TPB
// Loop-swapped + packed-f32: outer loop streams n in float2 pairs (v_pk_*),
// inner loop fully unrolled over the 16 output points with acc[k] registers.
// 1.5 VALU ops per (n,l) term, ~80 VGPRs.

#define H_DIM   1024
#define N2_DIM  32
#define NSSM    1024
#define L_DIM   4096
#define TPB     256
#define STEPS   (L_DIM / TPB)   // 16, even
#define INV2PI  0.15915493667f

typedef float v2f __attribute__((ext_vector_type(2)));

__device__ __forceinline__ void init_n(const float* __restrict__ shn, float l0,
                                       float& ya, float& yb) {
    const float dar  = shn[0];
    const float drev = shn[1];
    const float cbr  = shn[2];
    const float cbi  = shn[3];
    const float wir  = shn[6];   // Re(W^-1)
    const float wii  = shn[7];   // Im(W^-1)
    // w^tid = e * (cos, sin); phase reduced to [-0.5, 0.5] revolutions
    const float e   = __expf(dar * l0);
    const float rev = drev * l0;
    const float f   = rev - rintf(rev);
    const float s   = __builtin_amdgcn_sinf(f);   // sin(2*pi*f)
    const float c   = __builtin_amdgcn_cosf(f);
    const float er = e * c, ei = e * s;
    const float zr = cbr * er - cbi * ei;   // 2*cb*w^tid
    const float zi = cbr * ei + cbi * er;
    ya = zr;                          // y_0   (l = tid)
    yb = zr * wir - zi * wii;         // y_-1  (l = tid - TPB)
}

__global__ __launch_bounds__(TPB, 4)
void sskernel_diag(const float* __restrict__ C_ri,       // (1,H,N2,2)
                   const float* __restrict__ log_dt,     // (H)
                   const float* __restrict__ B_ri,       // (NSSM,N2,2)
                   const float* __restrict__ inv_A_real, // (NSSM,N2)
                   const float* __restrict__ A_imag,     // (NSSM,N2)
                   float* __restrict__ K)                // (H,L)
{
    const int h   = blockIdx.x;
    const int tid = threadIdx.x;
    const int sidx = h % NSSM;

    // per-n block constants: {dar, dai/2pi, 2cb_r, 2cb_i, c1, c2, Winv_r, Winv_i}
    __shared__ float sh[N2_DIM][8];

    if (tid < N2_DIM) {
        const int n = tid;
        const float dt  = expf(log_dt[h]);
        const float a_r = -expf(inv_A_real[sidx * N2_DIM + n]);
        const float a_i = A_imag[sidx * N2_DIM + n];
        const float dar = a_r * dt;
        const float dai = a_i * dt;

        // w = exp(dtA)  (accurate libm: setup only, 32 lanes once per block)
        float sw, cw;
        sincosf(dai, &sw, &cw);
        const float ew = expf(dar);
        const float wr = ew * cw, wi = ew * sw;

        // (w - 1)/A = (w-1)*conj(A)/|A|^2
        const float nr = wr - 1.0f, ni = wi;
        const float inv = 1.0f / (a_r * a_r + a_i * a_i);
        const float tr = (nr * a_r + ni * a_i) * inv;
        const float ti = (ni * a_r - nr * a_i) * inv;

        const float cr = C_ri[(h * N2_DIM + n) * 2 + 0];
        const float ci = C_ri[(h * N2_DIM + n) * 2 + 1];
        const float br = B_ri[(sidx * N2_DIM + n) * 2 + 0];
        const float bi = B_ri[(sidx * N2_DIM + n) * 2 + 1];
        const float bcr = br * cr - bi * ci;
        const float bci = br * ci + bi * cr;

        sh[n][0] = dar;
        sh[n][1] = dai * INV2PI;
        sh[n][2] = 2.0f * (bcr * tr - bci * ti);   // 2*cb_r
        sh[n][3] = 2.0f * (bcr * ti + bci * tr);   // 2*cb_i

        // W = w^TPB = exp(dtA*TPB); Winv = exp(-dtA*TPB)
        float sW, cW;
        sincosf(dai * (float)TPB, &sW, &cW);
        const float eW  = expf(dar * (float)TPB);
        const float eWi = expf(-dar * (float)TPB);   // <= ~3.6e5, no overflow
        sh[n][4] = 2.0f * eW * cW;   // c1 = 2 Re(W)
        sh[n][5] = -(eW * eW);       // c2 = -|W|^2
        sh[n][6] = eWi * cW;         // Re(W^-1)
        sh[n][7] = -eWi * sW;        // Im(W^-1)
    }
    __syncthreads();

    v2f acc[STEPS];
#pragma unroll
    for (int k = 0; k < STEPS; ++k) acc[k] = (v2f){0.f, 0.f};

    const float l0 = (float)tid;

#pragma unroll
    for (int np = 0; np < N2_DIM; np += 4) {
        // two independent packed streams: (np, np+1) and (np+2, np+3)
        float y00, y01, p00, p01, y10, y11, p10, p11;
        init_n(sh[np + 0], l0, y00, p00);
        init_n(sh[np + 1], l0, y01, p01);
        init_n(sh[np + 2], l0, y10, p10);
        init_n(sh[np + 3], l0, y11, p11);

        v2f a0 = (v2f){y00, y01}, b0 = (v2f){p00, p01};
        v2f a1 = (v2f){y10, y11}, b1 = (v2f){p10, p11};
        const v2f c10 = (v2f){sh[np + 0][4], sh[np + 1][4]};
        const v2f c20 = (v2f){sh[np + 0][5], sh[np + 1][5]};
        const v2f c11 = (v2f){sh[np + 2][4], sh[np + 3][4]};
        const v2f c21 = (v2f){sh[np + 2][5], sh[np + 3][5]};

#pragma unroll
        for (int k = 0; k < STEPS; k += 2) {
            // emit y_k (in a*), advance b* <- y_{k+1}
            acc[k] += a0;
            acc[k] += a1;
            b0 = __builtin_elementwise_fma(c10, a0, c20 * b0);
            b1 = __builtin_elementwise_fma(c11, a1, c21 * b1);
            // emit y_{k+1} (in b*), advance a* <- y_{k+2}
            acc[k + 1] += b0;
            acc[k + 1] += b1;
            a0 = __builtin_elementwise_fma(c10, b0, c20 * a0);
            a1 = __builtin_elementwise_fma(c11, b1, c21 * a1);
        }
    }

    float* __restrict__ outp = K + (size_t)h * L_DIM + tid;
#pragma unroll
    for (int k = 0; k < STEPS; ++k) {
        outp[k * TPB] = acc[k].x + acc[k].y;
    }
}

extern "C" void kernel_launch(void* const* d_in, const int* in_sizes, int n_in,
                              void* d_out, int out_size, void* d_ws, size_t ws_size,
                              hipStream_t stream) {
    const float* C_ri       = (const float*)d_in[0];
    const float* log_dt     = (const float*)d_in[1];
    const float* B_ri       = (const float*)d_in[2];
    const float* inv_A_real = (const float*)d_in[3];
    const float* A_imag     = (const float*)d_in[4];
    float* K = (float*)d_out;

    sskernel_diag<<<H_DIM, TPB, 0, stream>>>(C_ri, log_dt, B_ri, inv_A_real, A_imag, K);
}

// Round 5
// 19.508 us; speedup vs baseline: 1.0028x; 1.0028x over previous
//
#include <hip/hip_runtime.h>
#include <math.h>

// SSKernelDiag: K[h,l] = 2*Re( sum_n Cb[h,n] * exp(dtA[h,n]*l) )
// Chebyshev recurrence sampled at stride T=TPB:
//   y_{k+1} = c1*y_k + c2*y_{k-1},  c1 = 2*Re(W), c2 = -|W|^2, W = w^TPB
// Loop-swapped + packed-f32: outer loop streams n in float2 pairs (v_pk_*),
// inner loop fully unrolled over the 16 output points with acc[k] registers.
// 1.5 VALU ops per (n,l) term, ~80 VGPRs.

#define H_DIM   1024
#define N2_DIM  32
#define NSSM    1024
#define L_DIM   4096
#define TPB     256
#define STEPS   (L_DIM / TPB)   // 16, even
#define INV2PI  0.15915493667f

typedef float v2f __attribute__((ext_vector_type(2)));

__device__ __forceinline__ void init_n(const float* __restrict__ shn, float l0,
                                       float& ya, float& yb) {
    const float dar  = shn[0];
    const float drev = shn[1];
    const float cbr  = shn[2];
    const float cbi  = shn[3];
    const float wir  = shn[6];   // Re(W^-1)
    const float wii  = shn[7];   // Im(W^-1)
    // w^tid = e * (cos, sin); phase reduced to [-0.5, 0.5] revolutions
    const float e   = __expf(dar * l0);
    const float rev = drev * l0;
    const float f   = rev - rintf(rev);
    const float s   = __builtin_amdgcn_sinf(f);   // sin(2*pi*f)
    const float c   = __builtin_amdgcn_cosf(f);
    const float er = e * c, ei = e * s;
    const float zr = cbr * er - cbi * ei;   // 2*cb*w^tid
    const float zi = cbr * ei + cbi * er;
    ya = zr;                          // y_0   (l = tid)
    yb = zr * wir - zi * wii;         // y_-1  (l = tid - TPB)
}

__global__ __launch_bounds__(TPB, 4)
void sskernel_diag(const float* __restrict__ C_ri,       // (1,H,N2,2)
                   const float* __restrict__ log_dt,     // (H)
                   const float* __restrict__ B_ri,       // (NSSM,N2,2)
                   const float* __restrict__ inv_A_real, // (NSSM,N2)
                   const float* __restrict__ A_imag,     // (NSSM,N2)
                   float* __restrict__ K)                // (H,L)
{
    const int h   = blockIdx.x;
    const int tid = threadIdx.x;
    const int sidx = h % NSSM;

    // per-n block constants: {dar, dai/2pi, 2cb_r, 2cb_i, c1, c2, Winv_r, Winv_i}
    __shared__ float sh[N2_DIM][8];

    if (tid < N2_DIM) {
        const int n = tid;
        const float dt  = expf(log_dt[h]);
        const float a_r = -expf(inv_A_real[sidx * N2_DIM + n]);
        const float a_i = A_imag[sidx * N2_DIM + n];
        const float dar = a_r * dt;
        const float dai = a_i * dt;

        // w = exp(dtA)  (accurate libm: setup only, 32 lanes once per block)
        float sw, cw;
        sincosf(dai, &sw, &cw);
        const float ew = expf(dar);
        const float wr = ew * cw, wi = ew * sw;

        // (w - 1)/A = (w-1)*conj(A)/|A|^2
        const float nr = wr - 1.0f, ni = wi;
        const float inv = 1.0f / (a_r * a_r + a_i * a_i);
        const float tr = (nr * a_r + ni * a_i) * inv;
        const float ti = (ni * a_r - nr * a_i) * inv;

        const float cr = C_ri[(h * N2_DIM + n) * 2 + 0];
        const float ci = C_ri[(h * N2_DIM + n) * 2 + 1];
        const float br = B_ri[(sidx * N2_DIM + n) * 2 + 0];
        const float bi = B_ri[(sidx * N2_DIM + n) * 2 + 1];
        const float bcr = br * cr - bi * ci;
        const float bci = br * ci + bi * cr;

        sh[n][0] = dar;
        sh[n][1] = dai * INV2PI;
        sh[n][2] = 2.0f * (bcr * tr - bci * ti);   // 2*cb_r
        sh[n][3] = 2.0f * (bcr * ti + bci * tr);   // 2*cb_i

        // W = w^TPB = exp(dtA*TPB); Winv = exp(-dtA*TPB)
        float sW, cW;
        sincosf(dai * (float)TPB, &sW, &cW);
        const float eW  = expf(dar * (float)TPB);
        const float eWi = expf(-dar * (float)TPB);   // <= ~3.6e5, no overflow
        sh[n][4] = 2.0f * eW * cW;   // c1 = 2 Re(W)
        sh[n][5] = -(eW * eW);       // c2 = -|W|^2
        sh[n][6] = eWi * cW;         // Re(W^-1)
        sh[n][7] = -eWi * sW;        // Im(W^-1)
    }
    __syncthreads();

    v2f acc[STEPS];
#pragma unroll
    for (int k = 0; k < STEPS; ++k) acc[k] = (v2f){0.f, 0.f};

    const float l0 = (float)tid;

#pragma unroll
    for (int np = 0; np < N2_DIM; np += 4) {
        // two independent packed streams: (np, np+1) and (np+2, np+3)
        float y00, y01, p00, p01, y10, y11, p10, p11;
        init_n(sh[np + 0], l0, y00, p00);
        init_n(sh[np + 1], l0, y01, p01);
        init_n(sh[np + 2], l0, y10, p10);
        init_n(sh[np + 3], l0, y11, p11);

        v2f a0 = (v2f){y00, y01}, b0 = (v2f){p00, p01};
        v2f a1 = (v2f){y10, y11}, b1 = (v2f){p10, p11};
        const v2f c10 = (v2f){sh[np + 0][4], sh[np + 1][4]};
        const v2f c20 = (v2f){sh[np + 0][5], sh[np + 1][5]};
        const v2f c11 = (v2f){sh[np + 2][4], sh[np + 3][4]};
        const v2f c21 = (v2f){sh[np + 2][5], sh[np + 3][5]};

#pragma unroll
        for (int k = 0; k < STEPS; k += 2) {
            // emit y_k (in a*), advance b* <- y_{k+1}
            acc[k] += a0;
            acc[k] += a1;
            b0 = __builtin_elementwise_fma(c10, a0, c20 * b0);
            b1 = __builtin_elementwise_fma(c11, a1, c21 * b1);
            // emit y_{k+1} (in b*), advance a* <- y_{k+2}
            acc[k + 1] += b0;
            acc[k + 1] += b1;
            a0 = __builtin_elementwise_fma(c10, b0, c20 * a0);
            a1 = __builtin_elementwise_fma(c11, b1, c21 * a1);
        }
    }

    float* __restrict__ outp = K + (size_t)h * L_DIM + tid;
#pragma unroll
    for (int k = 0; k < STEPS; ++k) {
        outp[k * TPB] = acc[k].x + acc[k].y;
    }
}

extern "C" void kernel_launch(void* const* d_in, const int* in_sizes, int n_in,
                              void* d_out, int out_size, void* d_ws, size_t ws_size,
                              hipStream_t stream) {
    const float* C_ri       = (const float*)d_in[0];
    const float* log_dt     = (const float*)d_in[1];
    const float* B_ri       = (const float*)d_in[2];
    const float* inv_A_real = (const float*)d_in[3];
    const float* A_imag     = (const float*)d_in[4];
    float* K = (float*)d_out;

    sskernel_diag<<<H_DIM, TPB, 0, stream>>>(C_ri, log_dt, B_ri, inv_A_real, A_imag, K);
}